// Round 8
// baseline (464.107 us; speedup 1.0000x reference)
//
#include <hip/hip_runtime.h>
#include <float.h>
#include <math.h>

#define D 512
#define VDIM 512
#define KSEL 32
#define BM 256
#define BN 256
#define BK 64
#define CAP 2048
#define TSEL 48
#define TAU 0.11f
#define ROWSLOTS 16

typedef short bf16x8 __attribute__((ext_vector_type(8)));
typedef float f32x4 __attribute__((ext_vector_type(4)));
typedef const unsigned int __attribute__((address_space(1))) as1_uint;
typedef unsigned int __attribute__((address_space(3))) as3_uint;

// ---------- Kernel 1: norms + normalized-bf16 conversion (1 wave/row) ------
__global__ __launch_bounds__(256)
void k_prep(const float* __restrict__ queries, const float* __restrict__ keys,
            unsigned short* __restrict__ qbf, unsigned short* __restrict__ kbf,
            float* __restrict__ inv_nq, float* __restrict__ inv_nk, int B, int N) {
  const int wid = threadIdx.x >> 6, lane = threadIdx.x & 63;
  const int row = blockIdx.x * 4 + wid;
  if (row >= N + B) return;
  const bool iskey = row < N;
  const float* src = iskey ? keys + (size_t)row * D : queries + (size_t)(row - N) * D;
  float4 f0 = *(const float4*)(src + lane * 8);
  float4 f1 = *(const float4*)(src + lane * 8 + 4);
  float ss = f0.x*f0.x + f0.y*f0.y + f0.z*f0.z + f0.w*f0.w
           + f1.x*f1.x + f1.y*f1.y + f1.z*f1.z + f1.w*f1.w;
  #pragma unroll
  for (int off = 32; off; off >>= 1) ss += __shfl_xor(ss, off);
  const float inv = 1.0f / fmaxf(sqrtf(ss), 1e-8f);
  float sc[8] = {f0.x, f0.y, f0.z, f0.w, f1.x, f1.y, f1.z, f1.w};
  bf16x8 ov;
  #pragma unroll
  for (int e = 0; e < 8; ++e) {
    unsigned u = __float_as_uint(sc[e] * inv);
    u += 0x7fffu + ((u >> 16) & 1u);            // RNE to bf16
    ov[e] = (short)(u >> 16);
  }
  unsigned short* dst = (iskey ? kbf + (size_t)row * D
                               : qbf + (size_t)(row - N) * D) + lane * 8;
  *(bf16x8*)dst = ov;
  if (lane == 0) { if (iskey) inv_nk[row] = inv; else inv_nq[row - N] = inv; }
}

// ---------- Kernel 2: bf16 MFMA sims + threshold compaction -----------------
// 256x256 tile, 512 threads (8 waves 2Mx4N), double-buffered 128KB LDS.
// K-HALF pipelined schedule (T3+T4 together, first time):
//   stage-unit = (kt, kh) = A[:, kh-half] + B[:, kh-half] (32KB, 4 gloads/thr)
//   phase (kt, kh) consumes exactly unit (kt, kh)  -> need is UNIFORM per wave
//   unit issued at phase (kt-1, kh): 2 phases of latency cover
//   every phase: uniform s_waitcnt vmcnt(4)  (never drains to 0 in the loop)
//   1 barrier/phase (16 total); stage targets a region 2 barriers dead.
// LDS layout per k-half region (16KB): logical row r (0..255) x chunk c (0..3,
// 16B each, k = kh*32 + c*8): byte = (r>>1)*128 + (((c + 4*(r&1)) ^ ((r>>1)&7))*16.
// Full-wave ds_read_b128: 8 lanes per 4-bank group at distinct rows = 2/bank, free.
__global__ __launch_bounds__(512, 2)
void k_gemm_filter(const unsigned short* __restrict__ qbf,
                   const unsigned short* __restrict__ kbf,
                   float* __restrict__ cand, int* __restrict__ gcnt,
                   int B, int N) {
  __shared__ char lds[2 * 65536];   // [buf][A 32KB (kh0|kh1) | B 32KB (kh0|kh1)]
  const int t = threadIdx.x;
  const int lane = t & 63, wid = t >> 6;
  const int wr = wid >> 2, wc = wid & 3;        // 2 x 4 wave grid
  const int lr = lane & 15, lg = lane >> 4;

  const int nq = B / BM;                 // 8
  const int nk = (N + BN - 1) / BN;      // 391
  const int nwg = nq * nk;
  const int bid = blockIdx.x;
  // bijective XCD chunk swizzle (m204)
  const int qq = nwg >> 3, rr = nwg & 7;
  const int xcd = bid & 7, idx = bid >> 3;
  const int swz = (xcd < rr ? xcd * (qq + 1) : rr * (qq + 1) + (xcd - rr) * qq) + idx;
  const int qt = swz % nq, ktile = swz / nq;
  const int qbase = qt * BM;
  const int tile = ktile * BN;

  // --- staging precompute: decode linear LDS byte -> (logical row, chunk) ---
  // per k-half region: instr j in {0,1} covers bytes [j*8192, (j+1)*8192)
  const char* gA[2]; const char* gB[2]; int ldA[2], ldB[2];
  #pragma unroll
  for (int j = 0; j < 2; ++j) {
    int lb = j * 8192 + t * 16;
    int R = lb >> 7;                     // LDS row (0..127)
    int s = (lb >> 4) & 7;               // stored chunk slot
    int cr = s ^ (R & 7);                // c + 4*(r&1)
    int r = 2 * R + ((cr >> 2) & 1);     // logical row 0..255
    int c = cr & 3;                      // 16B chunk within k-half
    gA[j] = (const char*)qbf + (size_t)(qbase + r) * 1024 + c * 16;
    gB[j] = (const char*)kbf + (size_t)min(tile + r, N - 1) * 1024 + c * 16;
    ldA[j] = j * 8192 + wid * 1024;      // + buf*65536 + kh*16384
    ldB[j] = 32768 + j * 8192 + wid * 1024;
  }

  // --- ds_read lane constants ---
  const int laneByte = (lr >> 1) * 128 + (((lg + 4 * (lr & 1)) ^ ((lr >> 1) & 7)) * 16);
  const int aWaveOff = wr * 8192;        // + m*1024
  const int bWaveOff = 32768 + wc * 4096; // + n*1024

  f32x4 acc[8][4];
  #pragma unroll
  for (int m = 0; m < 8; ++m)
    #pragma unroll
    for (int n = 0; n < 4; ++n) acc[m][n] = (f32x4)0.0f;

  auto STAGE = [&](int kt, int kh, int buf) {   // one unit: 4 gloads
    const int off = kt * 128 + kh * 64;
    const int dbase = buf * 65536 + kh * 16384;
    #pragma unroll
    for (int j = 0; j < 2; ++j) {
      __builtin_amdgcn_global_load_lds((as1_uint*)(const void*)(gA[j] + off),
                                       (as3_uint*)(void*)(lds + dbase + ldA[j]), 16, 0, 0);
      __builtin_amdgcn_global_load_lds((as1_uint*)(const void*)(gB[j] + off),
                                       (as3_uint*)(void*)(lds + dbase + ldB[j]), 16, 0, 0);
    }
  };

  // prologue: stage both units of tile 0 into buf 0
  STAGE(0, 0, 0);
  STAGE(0, 1, 0);

  #pragma unroll 1
  for (int kt = 0; kt < D / BK; ++kt) {
    const int buf = kt & 1;
    const int nbuf = buf ^ 1;
    const int nkt = (kt + 1) & 7;        // kt=7 dummy-stages tile 0 (dead buffer)
    #pragma unroll
    for (int kh = 0; kh < 2; ++kh) {
      asm volatile("s_waitcnt vmcnt(4)" ::: "memory");  // unit (kt,kh) landed
      __builtin_amdgcn_s_barrier();                     // ...for all waves
      asm volatile("" ::: "memory");
      STAGE(nkt, kh, nbuf);              // issue unit (kt+1, kh): 2 phases ahead
      const char* abase = lds + buf * 65536 + kh * 16384 + aWaveOff + laneByte;
      const char* bbase = lds + buf * 65536 + kh * 16384 + bWaveOff + laneByte;
      bf16x8 a[8], b[4];
      #pragma unroll
      for (int m = 0; m < 8; ++m) a[m] = *(const bf16x8*)(abase + m * 1024);
      #pragma unroll
      for (int n = 0; n < 4; ++n) b[n] = *(const bf16x8*)(bbase + n * 1024);
      __builtin_amdgcn_s_setprio(1);
      #pragma unroll
      for (int m = 0; m < 8; ++m)
        #pragma unroll
        for (int n = 0; n < 4; ++n)
          acc[m][n] = __builtin_amdgcn_mfma_f32_16x16x32_bf16(a[m], b[n], acc[m][n], 0, 0, 0);
      __builtin_amdgcn_s_setprio(0);
      asm volatile("" ::: "memory");
    }
  }

  // ---- epilogue: two-level compaction of sims >= TAU ----
  __syncthreads();   // drains vmcnt(0) (incl. dummy stages) before LDS reuse
  unsigned int* rowcnt = (unsigned int*)lds;                 // 256 x u32 (1KB)
  float2* rowlist = (float2*)(lds + 1024);                   // 256 x 16 x 8B (32KB)
  if (t < BM) rowcnt[t] = 0;
  __syncthreads();
  // C/D layout: col=lane&15 (lr), row=(lane>>4)*4+reg (lg*4+j)
  #pragma unroll
  for (int m = 0; m < 8; ++m) {
    #pragma unroll
    for (int j = 0; j < 4; ++j) {
      int rl = wr * 128 + m * 16 + lg * 4 + j;   // local query row 0..255
      #pragma unroll
      for (int n = 0; n < 4; ++n) {
        float v = acc[m][n][j];
        int kg = tile + wc * 64 + n * 16 + lr;
        if (v >= TAU && kg < N) {
          unsigned int p = atomicAdd(&rowcnt[rl], 1u);       // LDS atomic
          if (p < ROWSLOTS) {
            float2 e; e.x = v; e.y = __int_as_float(kg);
            rowlist[rl * ROWSLOTS + p] = e;
          }
        }
      }
    }
  }
  __syncthreads();
  // one global atomic per query row with hits; copy list out
  if (t < BM) {
    unsigned int cnt = rowcnt[t];
    if (cnt > ROWSLOTS) cnt = ROWSLOTS;
    if (cnt) {
      int qg = qbase + t;
      int pos = atomicAdd(&gcnt[qg], (int)cnt);
      #pragma unroll 1
      for (unsigned int i = 0; i < cnt; ++i) {
        if (pos + (int)i < CAP)
          *(float2*)&cand[((size_t)qg * CAP + pos + i) * 2] = rowlist[t * ROWSLOTS + i];
      }
    }
  }
}

// ---------- Kernel 3: merge -> approx top-48 -> exact rescore -> output -----
__global__ __launch_bounds__(256)
void k_merge_rescore(const float* __restrict__ cand, const int* __restrict__ gcnt,
                     const float* __restrict__ queries, const float* __restrict__ keys,
                     const float* __restrict__ values,
                     const float* __restrict__ inv_nq, const float* __restrict__ inv_nk,
                     float* __restrict__ out, int B, int N) {
  __shared__ float cv[CAP]; __shared__ int ci[CAP];
  __shared__ float qrow[D];
  __shared__ float wv[4]; __shared__ int wp[4];
  __shared__ int sel[TSEL]; __shared__ float exacts[TSEL];
  __shared__ float topv[KSEL]; __shared__ int topi[KSEL];
  __shared__ float wts[KSEL]; __shared__ float inv_sum_s;
  const int t = threadIdx.x, lane = t & 63, wid = t >> 6;
  const int q = blockIdx.x;
  const int cnt = min(gcnt[q], CAP);
  for (int p = t; p < D; p += 256) qrow[p] = queries[(size_t)q * D + p];
  for (int p = t; p < cnt; p += 256) {
    float2 e = *(const float2*)&cand[((size_t)q * CAP + p) * 2];
    cv[p] = e.x; ci[p] = __float_as_int(e.y);
  }
  if (t < TSEL) sel[t] = -1;
  __syncthreads();
  for (int r = 0; r < TSEL; ++r) {
    float bv = -FLT_MAX; int bp = -1;
    for (int p = t; p < cnt; p += 256) { float v = cv[p]; if (v > bv) { bv = v; bp = p; } }
    #pragma unroll
    for (int off = 32; off; off >>= 1) {
      float ov = __shfl_xor(bv, off); int op = __shfl_xor(bp, off);
      if (ov > bv) { bv = ov; bp = op; }
    }
    if (lane == 0) { wv[wid] = bv; wp[wid] = bp; }
    __syncthreads();
    if (t == 0) {
      float fb = wv[0]; int fp = wp[0];
      for (int w = 1; w < 4; ++w) if (wv[w] > fb) { fb = wv[w]; fp = wp[w]; }
      if (fp >= 0) { sel[r] = ci[fp]; cv[fp] = -FLT_MAX; }
    }
    __syncthreads();
  }
  // exact fp32 rescore (12 rows per wave)
  const float invq = inv_nq[q];
  #pragma unroll 1
  for (int i = 0; i < TSEL / 4; ++i) {
    int j = wid * (TSEL / 4) + i;
    int idx = sel[j];
    float dotv = 0.f;
    if (idx >= 0) {
      const float4* kr = (const float4*)(keys + (size_t)idx * D);
      float4 k0 = kr[lane * 2], k1 = kr[lane * 2 + 1];
      float4 q0 = *(const float4*)&qrow[lane * 8];
      float4 q1 = *(const float4*)&qrow[lane * 8 + 4];
      dotv = q0.x*k0.x + q0.y*k0.y + q0.z*k0.z + q0.w*k0.w
           + q1.x*k1.x + q1.y*k1.y + q1.z*k1.z + q1.w*k1.w;
      #pragma unroll
      for (int off = 32; off; off >>= 1) dotv += __shfl_xor(dotv, off);
    }
    if (lane == 0) exacts[j] = (idx >= 0) ? dotv * invq * inv_nk[idx] : -FLT_MAX;
  }
  __syncthreads();
  // exact sorted top-32 (wave 0)
  if (wid == 0) {
    float v = (lane < TSEL) ? exacts[lane] : -FLT_MAX;
    int myi = (lane < TSEL) ? sel[lane] : -1;
    for (int r = 0; r < KSEL; ++r) {
      float bv = v; int bl = lane;
      #pragma unroll
      for (int off = 32; off; off >>= 1) {
        float ov = __shfl_xor(bv, off); int ol = __shfl_xor(bl, off);
        if (ov > bv || (ov == bv && ol < bl)) { bv = ov; bl = ol; }
      }
      if (lane == 0) topv[r] = bv;
      if (lane == bl) { topi[r] = myi; v = -FLT_MAX; }
    }
  }
  __syncthreads();
  if (t == 0) {
    float mx = topv[0], sum = 0.f;
    for (int r = 0; r < KSEL; ++r) { float w = expf(topv[r] - mx); wts[r] = w; sum += w; }
    inv_sum_s = 1.0f / sum;
  }
  __syncthreads();
  const float inv_sum = inv_sum_s;
  float a0 = 0.f, a1 = 0.f;
  #pragma unroll 1
  for (int r = 0; r < KSEL; ++r) {
    const float* vr = values + (size_t)topi[r] * VDIM;
    float w = wts[r];
    a0 += w * vr[t]; a1 += w * vr[t + 256];
  }
  out[(size_t)q * VDIM + t] = a0 * inv_sum;
  out[(size_t)q * VDIM + t + 256] = a1 * inv_sum;
  if (t < KSEL) out[(size_t)B * VDIM + (size_t)q * KSEL + t] = topv[t];
}

extern "C" void kernel_launch(void* const* d_in, const int* in_sizes, int n_in,
                              void* d_out, int out_size, void* d_ws, size_t ws_size,
                              hipStream_t stream) {
  const float* queries = (const float*)d_in[0];
  const float* keys    = (const float*)d_in[1];
  const float* values  = (const float*)d_in[2];
  const int B = in_sizes[0] / D;     // 2048
  const int N = in_sizes[1] / D;     // 100000
  char* ws = (char*)d_ws;
  size_t o = 0;
  unsigned short* kbf = (unsigned short*)(ws + o); o += (size_t)N * D * 2; o = (o + 255) & ~(size_t)255;
  unsigned short* qbf = (unsigned short*)(ws + o); o += (size_t)B * D * 2; o = (o + 255) & ~(size_t)255;
  float* inv_nk = (float*)(ws + o); o += (size_t)N * 4; o = (o + 255) & ~(size_t)255;
  float* inv_nq = (float*)(ws + o); o += (size_t)B * 4; o = (o + 255) & ~(size_t)255;
  int*   gcnt   = (int*)(ws + o);   o += (size_t)B * 4; o = (o + 255) & ~(size_t)255;
  float* cand   = (float*)(ws + o); o += (size_t)B * CAP * 8;
  float* out = (float*)d_out;

  hipMemsetAsync(gcnt, 0, B * sizeof(int), stream);
  k_prep<<<(N + B + 3) / 4, 256, 0, stream>>>(queries, keys, qbf, kbf, inv_nq, inv_nk, B, N);
  const int nq = B / BM, nk = (N + BN - 1) / BN;
  k_gemm_filter<<<nq * nk, 512, 0, stream>>>(qbf, kbf, cand, gcnt, B, N);
  k_merge_rescore<<<B, 256, 0, stream>>>(cand, gcnt, queries, keys, values,
                                         inv_nq, inv_nk, out, B, N);
}